// Round 3
// baseline (1048.052 us; speedup 1.0000x reference)
//
#include <hip/hip_runtime.h>

namespace {

constexpr int Bsz = 4, Tsz = 2048, Hsz = 32, Csz = 64, DT = 16, NT = 128;

__device__ __forceinline__ float dot4(const float4 a, const float4 b) {
  return fmaf(a.x, b.x, fmaf(a.y, b.y, fmaf(a.z, b.z, a.w * b.w)));
}
__device__ __forceinline__ float4 ld4(const float* p) { return *(const float4*)p; }
__device__ __forceinline__ void st4(float* p, float4 v) { *(float4*)p = v; }

__global__ __launch_bounds__(256, 1)
void rwkv7_fp32_kernel(const float* __restrict__ gw, const float* __restrict__ gq,
                       const float* __restrict__ gk, const float* __restrict__ gv,
                       const float* __restrict__ ga, const float* __restrict__ gb,
                       const float* __restrict__ gs0, float* __restrict__ gy)
{
  // LDS (pitches padded for bank behavior; all float4-aligned)
  __shared__ float sS[32][68];                                   // state slice [i][j]
  __shared__ float sWQ[16][68], sWA[16][68], sKW[16][68], sBW[16][68], sWd[16][68];
  __shared__ float sVt[32][20], sUt[32][20];                     // transposed [i][t]
  __shared__ float sPab[16][20], sPak[16][20], sPqb[16][20], sPqk[16][20];
  __shared__ float sABU[16][36], sY[16][36];
  __shared__ float sFW[64];

  const int p = blockIdx.x;
  // pair splits of the same head onto the same XCD (round-robin assumption):
  // p and p+8 share an XCD -> bh from (p>>4, p&7), split from bit 3.
  const int bh    = ((p >> 4) << 3) | (p & 7);   // 0..127
  const int split = (p >> 3) & 1;
  const int bb = bh >> 5;         // / H
  const int hh = bh & 31;         // % H
  const int tid = threadIdx.x;
  const int iC0 = split << 5;     // global channel offset of the i-slice

  // ---- load state slice (s0) ----
  {
    const int i = tid & 31, jo = (tid >> 5) << 3;
    const float* src = gs0 + (((bb * Hsz + hh) * Csz) + (iC0 + i)) * Csz + jo;
    st4(&sS[i][jo], ld4(src));
    st4(&sS[i][jo + 4], ld4(src + 4));
  }

  const int s  = tid >> 4;          // 0..15 (row within chunk)
  const int c4 = (tid & 15) << 2;   // 0,4,...,60 (channel quad)

#pragma unroll 1
  for (int n = 0; n < NT; ++n) {
    const int tb = n * DT;
    const int gofs = (((bb * Tsz) + tb + s) * Hsz + hh) * Csz;

    // ---- phase 1: loads, wd, cumprod, derived tiles ----
    const float4 w4 = ld4(gw + gofs + c4);
    float4 wd4;
    wd4.x = __expf(-__expf(w4.x));
    wd4.y = __expf(-__expf(w4.y));
    wd4.z = __expf(-__expf(w4.z));
    wd4.w = __expf(-__expf(w4.w));
    st4(&sWd[s][c4], wd4);
    __syncthreads();
    if (tid < 64) {       // serial cumprod down each channel column (in place)
      float run = 1.f;
#pragma unroll
      for (int s2 = 0; s2 < 16; ++s2) { run *= sWd[s2][tid]; sWd[s2][tid] = run; }
    }
    __syncthreads();
    {
      const float4 incl = ld4(&sWd[s][c4]);
      const float4 q4 = ld4(gq + gofs + c4);
      const float4 k4 = ld4(gk + gofs + c4);
      const float4 a4 = ld4(ga + gofs + c4);
      const float4 b4 = ld4(gb + gofs + c4);
      float4 ri, ipv, t;
      ri.x = __builtin_amdgcn_rcpf(incl.x); ri.y = __builtin_amdgcn_rcpf(incl.y);
      ri.z = __builtin_amdgcn_rcpf(incl.z); ri.w = __builtin_amdgcn_rcpf(incl.w);
      ipv.x = incl.x * __builtin_amdgcn_rcpf(wd4.x);   // incl_prev = incl / wd
      ipv.y = incl.y * __builtin_amdgcn_rcpf(wd4.y);
      ipv.z = incl.z * __builtin_amdgcn_rcpf(wd4.z);
      ipv.w = incl.w * __builtin_amdgcn_rcpf(wd4.w);
      t.x = q4.x * incl.x; t.y = q4.y * incl.y; t.z = q4.z * incl.z; t.w = q4.w * incl.w;
      st4(&sWQ[s][c4], t);
      t.x = a4.x * ipv.x; t.y = a4.y * ipv.y; t.z = a4.z * ipv.z; t.w = a4.w * ipv.w;
      st4(&sWA[s][c4], t);
      t.x = k4.x * ri.x; t.y = k4.y * ri.y; t.z = k4.z * ri.z; t.w = k4.w * ri.w;
      st4(&sKW[s][c4], t);
      t.x = b4.x * ri.x; t.y = b4.y * ri.y; t.z = b4.z * ri.z; t.w = b4.w * ri.w;
      st4(&sBW[s][c4], t);
      if (s == 15) st4(&sFW[c4], incl);   // fw = incl at last row
    }
    {
      const int i2 = (tid & 15) << 1;
      const float2 v2 = *(const float2*)(gv + gofs + iC0 + i2);
      sVt[i2][s] = v2.x; sVt[i2 + 1][s] = v2.y;
    }
    __syncthreads();

    // ---- phase 2: P matrices (16x16, K=64) ----
    {
      const int tt = tid >> 4, ss = tid & 15;
      float ab = 0.f, ak = 0.f, qb = 0.f, qk = 0.f;
#pragma unroll
      for (int j = 0; j < 64; j += 4) {
        const float4 wa4 = ld4(&sWA[tt][j]);
        const float4 wq4 = ld4(&sWQ[tt][j]);
        const float4 bw4 = ld4(&sBW[ss][j]);
        const float4 kw4 = ld4(&sKW[ss][j]);
        ab += dot4(wa4, bw4); ak += dot4(wa4, kw4);
        qb += dot4(wq4, bw4); qk += dot4(wq4, kw4);
      }
      const bool strict = (tt > ss), incm = (tt >= ss);
      sPab[tt][ss] = strict ? ab : 0.f;
      sPak[tt][ss] = strict ? ak : 0.f;
      sPqb[tt][ss] = incm ? qb : 0.f;
      sPqk[tt][ss] = incm ? qk : 0.f;
    }
    __syncthreads();

    // ---- phase 3: abu = ak@V + wa@S^T ; y_partial = qk@V + wq@S^T ----
    {
      const int tt = tid >> 4, ip = tid & 15;
      const int i0 = ip << 1, i1 = i0 + 1;
      float A0 = 0.f, A1 = 0.f, Y0 = 0.f, Y1 = 0.f;
#pragma unroll
      for (int j = 0; j < 64; j += 4) {
        const float4 wa4 = ld4(&sWA[tt][j]);
        const float4 wq4 = ld4(&sWQ[tt][j]);
        const float4 s0v = ld4(&sS[i0][j]);
        const float4 s1v = ld4(&sS[i1][j]);
        A0 += dot4(wa4, s0v); A1 += dot4(wa4, s1v);
        Y0 += dot4(wq4, s0v); Y1 += dot4(wq4, s1v);
      }
#pragma unroll
      for (int s2 = 0; s2 < 16; s2 += 4) {
        const float4 ak4 = ld4(&sPak[tt][s2]);
        const float4 qk4 = ld4(&sPqk[tt][s2]);
        const float4 v04 = ld4(&sVt[i0][s2]);
        const float4 v14 = ld4(&sVt[i1][s2]);
        A0 += dot4(ak4, v04); A1 += dot4(ak4, v14);
        Y0 += dot4(qk4, v04); Y1 += dot4(qk4, v14);
      }
      sABU[tt][i0] = A0; sABU[tt][i1] = A1;
      sY[tt][i0] = Y0;   sY[tt][i1] = Y1;
    }
    __syncthreads();

    // ---- phase 4: forward substitution (I - ab) u = abu, unit lower ----
    if (tid < 32) {
      const int i = tid;
      float u[16];
      u[0] = sABU[0][i];
#pragma unroll
      for (int t2 = 1; t2 < 16; ++t2) {
        float acc = sABU[t2][i];
#pragma unroll
        for (int s2 = 0; s2 < t2; ++s2) acc = fmaf(sPab[t2][s2], u[s2], acc);
        u[t2] = acc;
      }
      st4(&sUt[i][0],  make_float4(u[0],  u[1],  u[2],  u[3]));
      st4(&sUt[i][4],  make_float4(u[4],  u[5],  u[6],  u[7]));
      st4(&sUt[i][8],  make_float4(u[8],  u[9],  u[10], u[11]));
      st4(&sUt[i][12], make_float4(u[12], u[13], u[14], u[15]));
    }
    __syncthreads();

    // ---- phase 5: y = y_partial + qb@u ; store ----
    {
      const int tt = tid >> 4, ip = tid & 15;
      const int i0 = ip << 1, i1 = i0 + 1;
      float Y0 = sY[tt][i0], Y1 = sY[tt][i1];
#pragma unroll
      for (int s2 = 0; s2 < 16; s2 += 4) {
        const float4 qb4 = ld4(&sPqb[tt][s2]);
        const float4 u04 = ld4(&sUt[i0][s2]);
        const float4 u14 = ld4(&sUt[i1][s2]);
        Y0 += dot4(qb4, u04); Y1 += dot4(qb4, u14);
      }
      *(float2*)(gy + gofs + iC0 + i0) = make_float2(Y0, Y1);   // tt == s
    }

    // ---- phase 6: state update S = fw * (S + V^T@kwi + u^T@bwi) ----
    {
      const int i = tid & 31, jo = (tid >> 5) << 3;
      float4 acc0 = ld4(&sS[i][jo]);
      float4 acc1 = ld4(&sS[i][jo + 4]);
#pragma unroll
      for (int t2 = 0; t2 < 16; ++t2) {
        const float vv = sVt[i][t2];
        const float uu = sUt[i][t2];
        const float4 kw0 = ld4(&sKW[t2][jo]);
        const float4 kw1 = ld4(&sKW[t2][jo + 4]);
        const float4 bw0 = ld4(&sBW[t2][jo]);
        const float4 bw1 = ld4(&sBW[t2][jo + 4]);
        acc0.x = fmaf(vv, kw0.x, fmaf(uu, bw0.x, acc0.x));
        acc0.y = fmaf(vv, kw0.y, fmaf(uu, bw0.y, acc0.y));
        acc0.z = fmaf(vv, kw0.z, fmaf(uu, bw0.z, acc0.z));
        acc0.w = fmaf(vv, kw0.w, fmaf(uu, bw0.w, acc0.w));
        acc1.x = fmaf(vv, kw1.x, fmaf(uu, bw1.x, acc1.x));
        acc1.y = fmaf(vv, kw1.y, fmaf(uu, bw1.y, acc1.y));
        acc1.z = fmaf(vv, kw1.z, fmaf(uu, bw1.z, acc1.z));
        acc1.w = fmaf(vv, kw1.w, fmaf(uu, bw1.w, acc1.w));
      }
      const float4 fw0 = ld4(&sFW[jo]);
      const float4 fw1 = ld4(&sFW[jo + 4]);
      acc0.x *= fw0.x; acc0.y *= fw0.y; acc0.z *= fw0.z; acc0.w *= fw0.w;
      acc1.x *= fw1.x; acc1.y *= fw1.y; acc1.z *= fw1.z; acc1.w *= fw1.w;
      st4(&sS[i][jo], acc0);
      st4(&sS[i][jo + 4], acc1);
    }
    __syncthreads();
  }
}

} // namespace

extern "C" void kernel_launch(void* const* d_in, const int* in_sizes, int n_in,
                              void* d_out, int out_size, void* d_ws, size_t ws_size,
                              hipStream_t stream) {
  const float* w  = (const float*)d_in[0];
  const float* q  = (const float*)d_in[1];
  const float* k  = (const float*)d_in[2];
  const float* v  = (const float*)d_in[3];
  const float* a  = (const float*)d_in[4];
  const float* b  = (const float*)d_in[5];
  const float* s0 = (const float*)d_in[6];
  float* y = (float*)d_out;
  rwkv7_fp32_kernel<<<dim3(256), dim3(256), 0, stream>>>(w, q, k, v, a, b, s0, y);
}

// Round 5
// 697.995 us; speedup vs baseline: 1.5015x; 1.5015x over previous
//
#include <hip/hip_runtime.h>
#include <stdint.h>

namespace {

constexpr int Bsz = 4, Tsz = 2048, Hsz = 32, Csz = 64, DT = 16, NT = 128;

typedef __bf16 bf16_t;
typedef bf16_t bf16x8 __attribute__((ext_vector_type(8)));
typedef float f32x4 __attribute__((ext_vector_type(4)));

__device__ __forceinline__ float4 ld4(const float* p) { return *(const float4*)p; }
__device__ __forceinline__ void st4(float* p, float4 v) { *(float4*)p = v; }

__device__ __forceinline__ uint16_t f2bf(float x) {
  uint32_t u = __builtin_bit_cast(uint32_t, x);
  return (uint16_t)((u + 0x7FFFu + ((u >> 16) & 1u)) >> 16);
}
__device__ __forceinline__ float bf2f(uint16_t h) {
  uint32_t u = ((uint32_t)h) << 16;
  return __builtin_bit_cast(float, u);
}
__device__ __forceinline__ void cvthl(float x, uint16_t& h, uint16_t& l) {
  h = f2bf(x); l = f2bf(x - bf2f(h));
}
__device__ __forceinline__ bf16x8 ldf(const uint16_t* p) { return *(const bf16x8*)p; }

__device__ __forceinline__ f32x4 mfma_(bf16x8 a, bf16x8 b, f32x4 c) {
  return __builtin_amdgcn_mfma_f32_16x16x32_bf16(a, b, c, 0, 0, 0);
}
// hi/lo split-emulated fp32-ish matmul: D += Al*Bh + Ah*Bl + Ah*Bh
__device__ __forceinline__ f32x4 mfma3(bf16x8 ah, bf16x8 al, bf16x8 bh, bf16x8 bl, f32x4 c) {
  c = mfma_(al, bh, c);
  c = mfma_(ah, bl, c);
  c = mfma_(ah, bh, c);
  return c;
}

// Tile pitches (uint16_t elements). 72*2=144B rows (16B-mult, 2-way banks);
// 40*2=80B rows (16B-mult, 2-way banks).
constexpr int P72 = 72, P40 = 40;

__global__ __launch_bounds__(256, 1)
void rwkv7_mfma_kernel(const float* __restrict__ gw, const float* __restrict__ gq,
                       const float* __restrict__ gk, const float* __restrict__ gv,
                       const float* __restrict__ ga, const float* __restrict__ gb,
                       const float* __restrict__ gs0, float* __restrict__ gy)
{
  // row-major [16][72] bf16 tiles (K=64 real, pad): A/B operands of P-stage & stage-2
  __shared__ uint16_t sWAh[16*P72], sWAl[16*P72], sWQh[16*P72], sWQl[16*P72];
  __shared__ uint16_t sKWh[16*P72], sKWl[16*P72], sBWh[16*P72], sBWl[16*P72];
  // state bf16 mirror [32][72]
  __shared__ uint16_t sSh[32*P72], sSl[32*P72];
  // transposed [j][t'] tile (t'<16: kwi, t'>=16: bwi), [64][40]
  __shared__ uint16_t sKBh[64*P40], sKBl[64*P40];
  // transposed v / u: [i][t] [32][40] (cols 16..39 zero)
  __shared__ uint16_t sVth[32*P40], sVtl[32*P40], sUth[32*P40], sUtl[32*P40];
  // P-tiles [16][40] (cols 16..39 zero)
  __shared__ uint16_t sAKh[16*P40], sAKl[16*P40], sQKh[16*P40], sQKl[16*P40], sQBh[16*P40], sQBl[16*P40];
  __shared__ float sABf[16*17];    // ab fp32 for solve
  __shared__ float sABUf[16*33];   // ABU fp32 for solve
  __shared__ float sFW[64];
  __shared__ float sWdA[16*68];

  const int p = blockIdx.x;
  const int bh = ((p >> 4) << 3) | (p & 7);   // pair p,p+8 -> same head
  const int split = (p >> 3) & 1;
  const int bb = bh >> 5, hh = bh & 31;
  const int iC0 = split << 5;                 // this WG's v-channel window [iC0, iC0+32)
  const int tid = threadIdx.x;
  const int lane = tid & 63, wid = tid >> 6;
  const int s = tid >> 4, c4 = (tid & 15) << 2;
  const int l15 = lane & 15, kg = lane >> 4;

  // ---- one-time zero of K-pad regions (cols 16..39) ----
  for (int idx = tid; idx < 16 * 24; idx += 256) {
    int r = idx / 24, c = 16 + idx % 24;
    sAKh[r*P40+c] = 0; sAKl[r*P40+c] = 0; sQKh[r*P40+c] = 0;
    sQKl[r*P40+c] = 0; sQBh[r*P40+c] = 0; sQBl[r*P40+c] = 0;
  }
  for (int idx = tid; idx < 32 * 24; idx += 256) {
    int r = idx / 24, c = 16 + idx % 24;
    sVth[r*P40+c] = 0; sVtl[r*P40+c] = 0; sUth[r*P40+c] = 0; sUtl[r*P40+c] = 0;
  }

  // ---- initial state: fp32 frags in regs (waves 0,1) + bf16 mirror in LDS ----
  f32x4 Sreg[2][2];  // [mtile][n-subtile]; wave w owns j-cols [w*32, w*32+32)
  if (wid < 2) {
    const int jb = wid * 32;
#pragma unroll
    for (int mt = 0; mt < 2; ++mt)
#pragma unroll
      for (int nj = 0; nj < 2; ++nj) {
        f32x4 v = {};
#pragma unroll
        for (int r = 0; r < 4; ++r) {
          int i = mt * 16 + kg * 4 + r;
          int j = jb + nj * 16 + l15;
          float x = gs0[(((bb * Hsz + hh) * Csz) + iC0 + i) * Csz + j];
          v[r] = x;
          uint16_t h, l; cvthl(x, h, l);
          sSh[i * P72 + j] = h; sSl[i * P72 + j] = l;
        }
        Sreg[mt][nj] = v;
      }
  }

  // ---- preload chunk 0 ----
  const int cstep = DT * Hsz * Csz;                       // 32768
  const int base = ((bb * Tsz + s) * Hsz + hh) * Csz;    // row-s base of chunk 0
  const int i2 = (tid & 15) << 1;
  float4 w4 = ld4(gw + base + c4);
  float4 q4 = ld4(gq + base + c4);
  float4 k4 = ld4(gk + base + c4);
  float4 a4 = ld4(ga + base + c4);
  float4 b4 = ld4(gb + base + c4);
  float2 v2 = *(const float2*)(gv + base + iC0 + i2);

  f32x4 Yfrag = {};

  __syncthreads();

#pragma unroll 1
  for (int n = 0; n < NT; ++n) {
    // ---- R1: decay ----
    float4 wd4;
    wd4.x = __expf(-__expf(w4.x)); wd4.y = __expf(-__expf(w4.y));
    wd4.z = __expf(-__expf(w4.z)); wd4.w = __expf(-__expf(w4.w));
    st4(&sWdA[s * 68 + c4], wd4);
    __syncthreads();  // b1

    // ---- R2: redundant cumprod + derived tiles + scatters + prefetch ----
    {
      float4 run = make_float4(1.f, 1.f, 1.f, 1.f);
      float4 incl = run, ipv = run;
#pragma unroll
      for (int s2 = 0; s2 < 16; ++s2) {
        float4 d = ld4(&sWdA[s2 * 68 + c4]);
        bool at = (s2 == s);
        if (at) ipv = run;
        run.x *= d.x; run.y *= d.y; run.z *= d.z; run.w *= d.w;
        if (at) incl = run;
      }
      float4 fw4 = run;
      float4 ri;
      ri.x = __builtin_amdgcn_rcpf(incl.x); ri.y = __builtin_amdgcn_rcpf(incl.y);
      ri.z = __builtin_amdgcn_rcpf(incl.z); ri.w = __builtin_amdgcn_rcpf(incl.w);

      float wa[4] = { a4.x * ipv.x,  a4.y * ipv.y,  a4.z * ipv.z,  a4.w * ipv.w };
      float wq[4] = { q4.x * incl.x, q4.y * incl.y, q4.z * incl.z, q4.w * incl.w };
      float kw[4] = { k4.x * ri.x,   k4.y * ri.y,   k4.z * ri.z,   k4.w * ri.w };
      float bw[4] = { b4.x * ri.x,   b4.y * ri.y,   b4.z * ri.z,   b4.w * ri.w };

      ushort4 h4, l4;
      uint16_t h, l;
      // wa
      cvthl(wa[0], h4.x, l4.x); cvthl(wa[1], h4.y, l4.y); cvthl(wa[2], h4.z, l4.z); cvthl(wa[3], h4.w, l4.w);
      *(ushort4*)&sWAh[s * P72 + c4] = h4; *(ushort4*)&sWAl[s * P72 + c4] = l4;
      // wq
      cvthl(wq[0], h4.x, l4.x); cvthl(wq[1], h4.y, l4.y); cvthl(wq[2], h4.z, l4.z); cvthl(wq[3], h4.w, l4.w);
      *(ushort4*)&sWQh[s * P72 + c4] = h4; *(ushort4*)&sWQl[s * P72 + c4] = l4;
      // kw (row-major for P-stage) + transposed scatter into sKB
      cvthl(kw[0], h4.x, l4.x); cvthl(kw[1], h4.y, l4.y); cvthl(kw[2], h4.z, l4.z); cvthl(kw[3], h4.w, l4.w);
      *(ushort4*)&sKWh[s * P72 + c4] = h4; *(ushort4*)&sKWl[s * P72 + c4] = l4;
      sKBh[(c4 + 0) * P40 + s] = h4.x; sKBh[(c4 + 1) * P40 + s] = h4.y;
      sKBh[(c4 + 2) * P40 + s] = h4.z; sKBh[(c4 + 3) * P40 + s] = h4.w;
      sKBl[(c4 + 0) * P40 + s] = l4.x; sKBl[(c4 + 1) * P40 + s] = l4.y;
      sKBl[(c4 + 2) * P40 + s] = l4.z; sKBl[(c4 + 3) * P40 + s] = l4.w;
      // bw + transposed scatter (t' = 16 + s)
      cvthl(bw[0], h4.x, l4.x); cvthl(bw[1], h4.y, l4.y); cvthl(bw[2], h4.z, l4.z); cvthl(bw[3], h4.w, l4.w);
      *(ushort4*)&sBWh[s * P72 + c4] = h4; *(ushort4*)&sBWl[s * P72 + c4] = l4;
      sKBh[(c4 + 0) * P40 + 16 + s] = h4.x; sKBh[(c4 + 1) * P40 + 16 + s] = h4.y;
      sKBh[(c4 + 2) * P40 + 16 + s] = h4.z; sKBh[(c4 + 3) * P40 + 16 + s] = h4.w;
      sKBl[(c4 + 0) * P40 + 16 + s] = l4.x; sKBl[(c4 + 1) * P40 + 16 + s] = l4.y;
      sKBl[(c4 + 2) * P40 + 16 + s] = l4.z; sKBl[(c4 + 3) * P40 + 16 + s] = l4.w;
      // v transposed scatter
      cvthl(v2.x, h, l); sVth[(i2 + 0) * P40 + s] = h; sVtl[(i2 + 0) * P40 + s] = l;
      cvthl(v2.y, h, l); sVth[(i2 + 1) * P40 + s] = h; sVtl[(i2 + 1) * P40 + s] = l;
      if (s == 0) st4(&sFW[c4], fw4);
    }
    // prefetch chunk n+1 (consumed next iteration; covers HBM latency with MFMA phases)
    {
      const int nn = (n + 1 < NT) ? (n + 1) : n;
      const int gn = base + nn * cstep;
      w4 = ld4(gw + gn + c4); q4 = ld4(gq + gn + c4); k4 = ld4(gk + gn + c4);
      a4 = ld4(ga + gn + c4); b4 = ld4(gb + gn + c4);
      v2 = *(const float2*)(gv + gn + iC0 + i2);
    }
    __syncthreads();  // b2

    // ---- R3a: P-stage. wave0: ab(fp32), wave1: ak, wave2: qk, wave3: qb ----
    {
      const uint16_t* Ah = (wid < 2) ? sWAh : sWQh;
      const uint16_t* Al = (wid < 2) ? sWAl : sWQl;
      const bool useBW = (wid == 0) || (wid == 3);
      const uint16_t* Bh = useBW ? sBWh : sKWh;
      const uint16_t* Bl = useBW ? sBWl : sKWl;
      f32x4 acc = {};
#pragma unroll
      for (int ks = 0; ks < 2; ++ks) {
        bf16x8 aH = ldf(Ah + l15 * P72 + ks * 32 + kg * 8);
        bf16x8 aL = ldf(Al + l15 * P72 + ks * 32 + kg * 8);
        bf16x8 bH = ldf(Bh + l15 * P72 + ks * 32 + kg * 8);
        bf16x8 bL = ldf(Bl + l15 * P72 + ks * 32 + kg * 8);
        acc = mfma3(aH, aL, bH, bL, acc);
      }
#pragma unroll
      for (int r = 0; r < 4; ++r) {
        int t = kg * 4 + r, ss = l15;
        if (wid == 0) {
          sABf[t * 17 + ss] = (t > ss) ? acc[r] : 0.f;
        } else {
          bool keep = (wid == 1) ? (t > ss) : (t >= ss);
          float m = keep ? acc[r] : 0.f;
          uint16_t h, l; cvthl(m, h, l);
          uint16_t* th = (wid == 1) ? sAKh : (wid == 2) ? sQKh : sQBh;
          uint16_t* tl = (wid == 1) ? sAKl : (wid == 2) ? sQKl : sQBl;
          th[t * P40 + ss] = h; tl[t * P40 + ss] = l;
        }
      }
    }
    __syncthreads();  // b3

    // ---- R3b: ABU (waves 0,1) / Y-partial (waves 2,3) ----
    {
      const int nt = wid & 1;
      const int irow = nt * 16 + l15;
      const uint16_t* Ph = (wid < 2) ? sAKh : sQKh;
      const uint16_t* Pl = (wid < 2) ? sAKl : sQKl;
      const uint16_t* Wh = (wid < 2) ? sWAh : sWQh;
      const uint16_t* Wl = (wid < 2) ? sWAl : sWQl;
      f32x4 acc = {};
      {  // P@V part (K=32 incl zero-pad)
        bf16x8 aH = ldf(Ph + l15 * P40 + kg * 8);
        bf16x8 aL = ldf(Pl + l15 * P40 + kg * 8);
        bf16x8 bH = ldf(sVth + irow * P40 + kg * 8);
        bf16x8 bL = ldf(sVtl + irow * P40 + kg * 8);
        acc = mfma3(aH, aL, bH, bL, acc);
      }
#pragma unroll
      for (int ks = 0; ks < 2; ++ks) {  // W@S part (K=64)
        bf16x8 aH = ldf(Wh + l15 * P72 + ks * 32 + kg * 8);
        bf16x8 aL = ldf(Wl + l15 * P72 + ks * 32 + kg * 8);
        bf16x8 bH = ldf(sSh + irow * P72 + ks * 32 + kg * 8);
        bf16x8 bL = ldf(sSl + irow * P72 + ks * 32 + kg * 8);
        acc = mfma3(aH, aL, bH, bL, acc);
      }
      if (wid < 2) {
#pragma unroll
        for (int r = 0; r < 4; ++r) sABUf[(kg * 4 + r) * 33 + nt * 16 + l15] = acc[r];
      } else {
        Yfrag = acc;
      }
    }
    __syncthreads();  // b4

    // ---- solve (I - ab) u = ABU : wave0 lanes 0..31, one i each ----
    if (wid == 0 && lane < 32) {
      const int i = lane;
      float u[16];
      u[0] = sABUf[0 * 33 + i];
#pragma unroll
      for (int t = 1; t < 16; ++t) {
        float acc = sABUf[t * 33 + i];
#pragma unroll
        for (int ss = 0; ss < t; ++ss) acc = fmaf(sABf[t * 17 + ss], u[ss], acc);
        u[t] = acc;
      }
#pragma unroll
      for (int t = 0; t < 16; ++t) {
        uint16_t h, l; cvthl(u[t], h, l);
        sUth[i * P40 + t] = h; sUtl[i * P40 + t] = l;
      }
    }
    __syncthreads();  // b5

    // ---- R4: waves 2,3: y = Y + qb@u, store. waves 0,1: state update ----
    if (wid >= 2) {
      const int nt = wid & 1;
      const int irow = nt * 16 + l15;
      bf16x8 aH = ldf(sQBh + l15 * P40 + kg * 8);
      bf16x8 aL = ldf(sQBl + l15 * P40 + kg * 8);
      bf16x8 bH = ldf(sUth + irow * P40 + kg * 8);
      bf16x8 bL = ldf(sUtl + irow * P40 + kg * 8);
      Yfrag = mfma3(aH, aL, bH, bL, Yfrag);
#pragma unroll
      for (int r = 0; r < 4; ++r) {
        int t = kg * 4 + r;
        gy[((bb * Tsz + n * DT + t) * Hsz + hh) * Csz + iC0 + nt * 16 + l15] = Yfrag[r];
      }
    } else {
      const int jb = wid * 32;
#pragma unroll
      for (int mt = 0; mt < 2; ++mt) {
        const uint16_t* Abh = (kg < 2) ? sVth : sUth;   // A = [Vt | Ut], K=32
        const uint16_t* Abl = (kg < 2) ? sVtl : sUtl;
        const int ak = (kg & 1) * 8;
        bf16x8 aH = ldf(Abh + (mt * 16 + l15) * P40 + ak);
        bf16x8 aL = ldf(Abl + (mt * 16 + l15) * P40 + ak);
#pragma unroll
        for (int nj = 0; nj < 2; ++nj) {
          const int jt = jb + nj * 16;
          bf16x8 bH = ldf(sKBh + (jt + l15) * P40 + kg * 8);
          bf16x8 bL = ldf(sKBl + (jt + l15) * P40 + kg * 8);
          Sreg[mt][nj] = mfma3(aH, aL, bH, bL, Sreg[mt][nj]);
        }
      }
      // scale by fw and refresh bf16 mirror
#pragma unroll
      for (int mt = 0; mt < 2; ++mt)
#pragma unroll
        for (int nj = 0; nj < 2; ++nj) {
          int j = jb + nj * 16 + l15;
          float fwv = sFW[j];
#pragma unroll
          for (int r = 0; r < 4; ++r) {
            float x = Sreg[mt][nj][r] * fwv;
            Sreg[mt][nj][r] = x;
            int i = mt * 16 + kg * 4 + r;
            uint16_t h, l; cvthl(x, h, l);
            sSh[i * P72 + j] = h; sSl[i * P72 + j] = l;
          }
        }
    }
    __syncthreads();  // b6
  }
}

} // namespace

extern "C" void kernel_launch(void* const* d_in, const int* in_sizes, int n_in,
                              void* d_out, int out_size, void* d_ws, size_t ws_size,
                              hipStream_t stream) {
  const float* w  = (const float*)d_in[0];
  const float* q  = (const float*)d_in[1];
  const float* k  = (const float*)d_in[2];
  const float* v  = (const float*)d_in[3];
  const float* a  = (const float*)d_in[4];
  const float* b  = (const float*)d_in[5];
  const float* s0 = (const float*)d_in[6];
  float* y = (float*)d_out;
  rwkv7_mfma_kernel<<<dim3(256), dim3(256), 0, stream>>>(w, q, k, v, a, b, s0, y);
}